// Round 12
// baseline (694.776 us; speedup 1.0000x reference)
//
#include <hip/hip_runtime.h>

// ---------------- CSR construction (unchanged) ----------------

__global__ void count_kernel(const int* __restrict__ dst, int* __restrict__ counts, int E) {
    int e = blockIdx.x * 256 + threadIdx.x;
    if (e < E) atomicAdd(&counts[dst[e]], 1);
}

__global__ void scan_local(const int* __restrict__ counts, int* __restrict__ rowptr,
                           int* __restrict__ bsums, float* __restrict__ dinv, int N) {
    __shared__ int sm[256];
    int t = threadIdx.x;
    int gid = blockIdx.x * 256 + t;
    int v = (gid < N) ? counts[gid] : 0;
    if (gid < N) dinv[gid] = rsqrtf((float)v + 1.0f);
    int x = v;
    sm[t] = x; __syncthreads();
    for (int off = 1; off < 256; off <<= 1) {
        int y = (t >= off) ? sm[t - off] : 0;
        __syncthreads();
        x += y; sm[t] = x; __syncthreads();
    }
    if (gid < N) rowptr[gid] = x - v;
    if (t == 255) bsums[blockIdx.x] = x;
}

__global__ void scan_bsums(int* bsums, int nb) {
    __shared__ int sm[512];
    int t = threadIdx.x;
    int v = (t < nb) ? bsums[t] : 0;
    int x = v;
    sm[t] = x; __syncthreads();
    for (int off = 1; off < 512; off <<= 1) {
        int y = (t >= off) ? sm[t - off] : 0;
        __syncthreads();
        x += y; sm[t] = x; __syncthreads();
    }
    if (t < nb) bsums[t] = x - v;
}

__global__ void scan_add(int* __restrict__ rowptr, const int* __restrict__ bsums, int N) {
    int gid = blockIdx.x * 256 + threadIdx.x;
    if (gid < N) rowptr[gid] += bsums[blockIdx.x];
}

__global__ void fill_kernel(const int* __restrict__ src, const int* __restrict__ dst,
                            const int* __restrict__ rowptr, int* __restrict__ fillc,
                            const float* __restrict__ dinv,
                            int* __restrict__ csr, float* __restrict__ csrw, int E) {
    int e = blockIdx.x * 256 + threadIdx.x;
    if (e < E) {
        int d = dst[e];
        int s = src[e];
        int pos = rowptr[d] + atomicAdd(&fillc[d], 1);
        csr[pos] = s;
        csrw[pos] = dinv[s];
    }
}

// ------- layer 1 (algebraic fusion, spill-safe epilogues):
//         Y = relu(agg(X)@W1 + b1) @ W2        [agg(X@W1) == agg(X)@W1]
// Gather loop = R6's clean 1-wide shuffle loop. Both 64-iter epilogue matmuls
// are "#pragma unroll 4": full unroll lets the scheduler hoist all 64 loads
// (~256 live VGPRs) -> scratch spill -> GB-scale HBM traffic (R8/R9/R10).

__global__ void agg_layer1_kernel(const float* __restrict__ X, const int* __restrict__ csr,
                                  const float* __restrict__ csrw,
                                  const int* __restrict__ rowptr, const int* __restrict__ counts,
                                  const float* __restrict__ dinv, const float* __restrict__ W1,
                                  const float* __restrict__ b1, const float* __restrict__ W2,
                                  float* __restrict__ Y, int N) {
    __shared__ float W1l[64 * 64];
    __shared__ float W2l[64 * 64];
    int tid = threadIdx.x;
    for (int i = tid; i < 4096; i += 256) { W1l[i] = W1[i]; W2l[i] = W2[i]; }
    __syncthreads();
    int lane = tid & 63, wave = tid >> 6;
    float bb = b1[lane];
    int v0 = blockIdx.x * 4 + wave;
    int stride = gridDim.x * 4;
    for (int v = v0; v < N; v += stride) {
        int start = rowptr[v], cnt = counts[v];
        float dv = dinv[v];
        float acc = dv * X[(size_t)v * 64 + lane];
        for (int base = 0; base < cnt; base += 64) {
            int nb = min(64, cnt - base);
            int idx = 0; float ds = 0.f;
            if (lane < nb) {
                idx = csr[start + base + lane];     // coalesced
                ds  = csrw[start + base + lane];    // coalesced
            }
            for (int j = 0; j < nb; ++j) {
                int s = __shfl(idx, j);
                float d = __shfl(ds, j);
                acc = fmaf(d, X[(size_t)s * 64 + lane], acc);
            }
        }
        float z = dv * acc;                        // agg(X) row, lane = feature
        float h = bb;                              // h1 = relu(z @ W1 + b1)
#pragma unroll 4
        for (int k = 0; k < 64; ++k)
            h = fmaf(__shfl(z, k), W1l[k * 64 + lane], h);
        h = fmaxf(h, 0.f);
        float y = 0.f;                             // Y = h1 @ W2
#pragma unroll 4
        for (int k = 0; k < 64; ++k)
            y = fmaf(__shfl(h, k), W2l[k * 64 + lane], y);
        Y[(size_t)v * 64 + lane] = y;
    }
}

// ------- layer2 agg fused with MLP head (R6/R11 version, byte-identical) -------

__global__ void agg_head_kernel(const float* __restrict__ Yin, const int* __restrict__ csr,
                                const float* __restrict__ csrw,
                                const int* __restrict__ rowptr, const int* __restrict__ counts,
                                const float* __restrict__ dinv, const float* __restrict__ b2,
                                const float* __restrict__ dW1, const float* __restrict__ db1,
                                const float* __restrict__ dW2, const float* __restrict__ db2,
                                float* __restrict__ out, int N) {
    __shared__ float D1[64 * 64];
    int tid = threadIdx.x;
    for (int i = tid; i < 4096; i += 256) D1[i] = dW1[i];
    __syncthreads();
    int lane = tid & 63, wave = tid >> 6;
    int c = lane & 15, part = lane >> 4;
    float d2r[16];
#pragma unroll
    for (int kk = 0; kk < 16; ++kk) d2r[kk] = dW2[(part * 16 + kk) * 16 + c];
    float bbl = b2[lane];
    float bb1 = db1[lane];
    float ob  = db2[c];
    int v0 = blockIdx.x * 4 + wave;
    int stride = gridDim.x * 4;
    for (int v = v0; v < N; v += stride) {
        int start = rowptr[v], cnt = counts[v];
        float dv = dinv[v];
        float acc = dv * Yin[(size_t)v * 64 + lane];
        for (int base = 0; base < cnt; base += 64) {
            int nb = min(64, cnt - base);
            int idx = 0; float ds = 0.f;
            if (lane < nb) {
                idx = csr[start + base + lane];
                ds  = csrw[start + base + lane];
            }
            for (int jj = 0; jj < nb; ++jj) {
                int s = __shfl(idx, jj);
                float d = __shfl(ds, jj);
                acc = fmaf(d, Yin[(size_t)s * 64 + lane], acc);
            }
        }
        float h2 = fmaxf(fmaf(dv, acc, bbl), 0.f);   // relu(agg + b2)
        float a1 = bb1;
#pragma unroll
        for (int k = 0; k < 64; ++k)
            a1 = fmaf(__shfl(h2, k), D1[k * 64 + lane], a1);
        a1 = fmaxf(a1, 0.f);
        float o = 0.f;
#pragma unroll
        for (int kk = 0; kk < 16; ++kk)
            o = fmaf(__shfl(a1, part * 16 + kk), d2r[kk], o);
        o += __shfl_xor(o, 16);
        o += __shfl_xor(o, 32);
        if (lane < 16) out[(size_t)v * 16 + lane] = o + ob;
    }
}

// ---------------- launch ----------------

extern "C" void kernel_launch(void* const* d_in, const int* in_sizes, int n_in,
                              void* d_out, int out_size, void* d_ws, size_t ws_size,
                              hipStream_t stream) {
    const float* x   = (const float*)d_in[0];
    const int*   ei  = (const int*)d_in[1];
    const float* W1  = (const float*)d_in[2];
    const float* b1  = (const float*)d_in[3];
    const float* W2  = (const float*)d_in[4];
    const float* b2  = (const float*)d_in[5];
    const float* dW1 = (const float*)d_in[6];
    const float* db1 = (const float*)d_in[7];
    const float* dW2 = (const float*)d_in[8];
    const float* db2 = (const float*)d_in[9];
    float* out = (float*)d_out;

    int N = in_sizes[0] / 64;
    int E = in_sizes[1] / 2;
    const int* src = ei;
    const int* dst = ei + E;

    size_t off = 0;
    auto alloc = [&](size_t bytes) {
        void* p = (char*)d_ws + off;
        off += (bytes + 511) & ~(size_t)511;
        return p;
    };
    int*   counts = (int*)alloc((size_t)N * 4);
    int*   fillc  = (int*)alloc((size_t)N * 4);
    int*   rowptr = (int*)alloc((size_t)N * 4);
    int*   bsums  = (int*)alloc(512 * 4);
    int*   csr    = (int*)alloc((size_t)E * 4);
    float* csrw   = (float*)alloc((size_t)E * 4);
    float* dinv   = (float*)alloc((size_t)N * 4);
    float* yw     = (float*)alloc((size_t)N * 64 * 4);

    hipMemsetAsync(counts, 0, (size_t)N * 4, stream);
    hipMemsetAsync(fillc, 0, (size_t)N * 4, stream);

    int nbN = (N + 255) / 256;
    int nbE = (E + 255) / 256;

    count_kernel<<<nbE, 256, 0, stream>>>(dst, counts, E);
    scan_local<<<nbN, 256, 0, stream>>>(counts, rowptr, bsums, dinv, N);
    scan_bsums<<<1, 512, 0, stream>>>(bsums, nbN);
    scan_add<<<nbN, 256, 0, stream>>>(rowptr, bsums, N);
    fill_kernel<<<nbE, 256, 0, stream>>>(src, dst, rowptr, fillc, dinv, csr, csrw, E);

    agg_layer1_kernel<<<2048, 256, 0, stream>>>(x, csr, csrw, rowptr, counts, dinv,
                                                W1, b1, W2, yw, N);
    agg_head_kernel<<<2048, 256, 0, stream>>>(yw, csr, csrw, rowptr, counts, dinv, b2,
                                              dW1, db1, dW2, db2, out, N);
}

// Round 13
// 666.792 us; speedup vs baseline: 1.0420x; 1.0420x over previous
//
#include <hip/hip_runtime.h>

// ---------------- CSR construction ----------------

__global__ void count_kernel(const int* __restrict__ dst, int* __restrict__ counts, int E) {
    int e = blockIdx.x * 256 + threadIdx.x;
    if (e < E) atomicAdd(&counts[dst[e]], 1);
}

__global__ void scan_local(const int* __restrict__ counts, int* __restrict__ rowptr,
                           int* __restrict__ bsums, float* __restrict__ dinv, int N) {
    __shared__ int sm[256];
    int t = threadIdx.x;
    int gid = blockIdx.x * 256 + t;
    int v = (gid < N) ? counts[gid] : 0;
    if (gid < N) dinv[gid] = rsqrtf((float)v + 1.0f);
    int x = v;
    sm[t] = x; __syncthreads();
    for (int off = 1; off < 256; off <<= 1) {
        int y = (t >= off) ? sm[t - off] : 0;
        __syncthreads();
        x += y; sm[t] = x; __syncthreads();
    }
    if (gid < N) rowptr[gid] = x - v;
    if (t == 255) bsums[blockIdx.x] = x;
}

__global__ void scan_bsums(int* bsums, int nb) {
    __shared__ int sm[512];
    int t = threadIdx.x;
    int v = (t < nb) ? bsums[t] : 0;
    int x = v;
    sm[t] = x; __syncthreads();
    for (int off = 1; off < 512; off <<= 1) {
        int y = (t >= off) ? sm[t - off] : 0;
        __syncthreads();
        x += y; sm[t] = x; __syncthreads();
    }
    if (t < nb) bsums[t] = x - v;
}

__global__ void scan_add(int* __restrict__ rowptr, const int* __restrict__ bsums, int N) {
    int gid = blockIdx.x * 256 + threadIdx.x;
    if (gid < N) rowptr[gid] += bsums[blockIdx.x];
}

// Packed edge record: {src, bits(dinv[src])} — ONE 8B scatter instead of two
// independent 4B scatters (each 4B random store costs a full cacheline
// transaction; this halves fill's effective scatter traffic).
__global__ void fill_kernel(const int* __restrict__ src, const int* __restrict__ dst,
                            const int* __restrict__ rowptr, int* __restrict__ fillc,
                            const float* __restrict__ dinv,
                            int2* __restrict__ edges, int E) {
    int e = blockIdx.x * 256 + threadIdx.x;
    if (e < E) {
        int d = dst[e];
        int s = src[e];
        int pos = rowptr[d] + atomicAdd(&fillc[d], 1);
        edges[pos] = make_int2(s, __float_as_int(dinv[s]));
    }
}

// ---------------- xw = X @ W : LDS-transpose, unroll-capped (8) ----------------
// Full unroll of a 64-iter load loop -> scheduler hoists all loads -> scratch
// spill -> GB-scale phantom HBM traffic (R10). unroll 8 keeps ~40 live VGPRs.

__global__ void __launch_bounds__(128)
gemm64_kernel(const float* __restrict__ X, const float* __restrict__ W,
              float* __restrict__ out, int N) {
    __shared__ float Wl[64 * 64];
    __shared__ float hbuf[2][256];
    int tid = threadIdx.x;
    int lane = tid & 63;
    for (int i = tid; i < 4096; i += 128) Wl[i] = W[i];
    __syncthreads();
    int wi = __builtin_amdgcn_readfirstlane(tid >> 6);
    float* hb = &hbuf[wi][0];
    int g0 = blockIdx.x * 2 + wi;
    int ng = gridDim.x * 2;
    int NG = (N + 3) >> 2;
    for (int g = g0; g < NG; g += ng) {
        int v0 = g * 4;
        float x0 = (v0 + 0 < N) ? X[(size_t)(v0 + 0) * 64 + lane] : 0.f;
        float x1 = (v0 + 1 < N) ? X[(size_t)(v0 + 1) * 64 + lane] : 0.f;
        float x2 = (v0 + 2 < N) ? X[(size_t)(v0 + 2) * 64 + lane] : 0.f;
        float x3 = (v0 + 3 < N) ? X[(size_t)(v0 + 3) * 64 + lane] : 0.f;
        *(float4*)&hb[lane * 4] = make_float4(x0, x1, x2, x3);   // wave-private transpose
        float y0 = 0.f, y1 = 0.f, y2 = 0.f, y3 = 0.f;
#pragma unroll 8
        for (int k = 0; k < 64; ++k) {
            float4 hk = *(const float4*)&hb[k * 4];   // same-address broadcast (free)
            float w = Wl[k * 64 + lane];              // stride-1 (2-way alias, free)
            y0 = fmaf(hk.x, w, y0);
            y1 = fmaf(hk.y, w, y1);
            y2 = fmaf(hk.z, w, y2);
            y3 = fmaf(hk.w, w, y3);
        }
        if (v0 + 0 < N) out[(size_t)(v0 + 0) * 64 + lane] = y0;
        if (v0 + 1 < N) out[(size_t)(v0 + 1) * 64 + lane] = y1;
        if (v0 + 2 < N) out[(size_t)(v0 + 2) * 64 + lane] = y2;
        if (v0 + 3 < N) out[(size_t)(v0 + 3) * 64 + lane] = y3;
    }
}

// ------- layer1 agg fused with @W2 (R6 gather loop; int2 edge loads) -------
// NOTE: gathers from xw which gemm64 just wrote -> L2/L3 warm (R12 showed
// gathering the harness-restored cold X costs ~+60us; keep the separate gemm).

__global__ void agg_mm_kernel(const float* __restrict__ XW, const int2* __restrict__ edges,
                              const int* __restrict__ rowptr, const int* __restrict__ counts,
                              const float* __restrict__ dinv, const float* __restrict__ bias,
                              const float* __restrict__ W2, float* __restrict__ Y, int N) {
    __shared__ float Wl[64 * 64];
    int tid = threadIdx.x;
    for (int i = tid; i < 4096; i += 256) Wl[i] = W2[i];
    __syncthreads();
    int lane = tid & 63, wave = tid >> 6;
    float bb = bias[lane];
    int v0 = blockIdx.x * 4 + wave;
    int stride = gridDim.x * 4;
    for (int v = v0; v < N; v += stride) {
        int start = rowptr[v], cnt = counts[v];
        float dv = dinv[v];
        float acc = dv * XW[(size_t)v * 64 + lane];
        for (int base = 0; base < cnt; base += 64) {
            int nb = min(64, cnt - base);
            int idx = 0; float ds = 0.f;
            if (lane < nb) {
                int2 e = edges[start + base + lane];   // one coalesced 8B load
                idx = e.x;
                ds  = __int_as_float(e.y);
            }
            for (int j = 0; j < nb; ++j) {
                int s = __shfl(idx, j);
                float d = __shfl(ds, j);
                acc = fmaf(d, XW[(size_t)s * 64 + lane], acc);
            }
        }
        float h = fmaxf(fmaf(dv, acc, bb), 0.f);
        float y = 0.f;
#pragma unroll
        for (int k = 0; k < 64; ++k)
            y = fmaf(__shfl(h, k), Wl[k * 64 + lane], y);
        Y[(size_t)v * 64 + lane] = y;
    }
}

// ------- layer2 agg fused with MLP head (R6 body; int2 edge loads) -------

__global__ void agg_head_kernel(const float* __restrict__ Yin, const int2* __restrict__ edges,
                                const int* __restrict__ rowptr, const int* __restrict__ counts,
                                const float* __restrict__ dinv, const float* __restrict__ b2,
                                const float* __restrict__ dW1, const float* __restrict__ db1,
                                const float* __restrict__ dW2, const float* __restrict__ db2,
                                float* __restrict__ out, int N) {
    __shared__ float D1[64 * 64];
    int tid = threadIdx.x;
    for (int i = tid; i < 4096; i += 256) D1[i] = dW1[i];
    __syncthreads();
    int lane = tid & 63, wave = tid >> 6;
    int c = lane & 15, part = lane >> 4;
    float d2r[16];
#pragma unroll
    for (int kk = 0; kk < 16; ++kk) d2r[kk] = dW2[(part * 16 + kk) * 16 + c];
    float bbl = b2[lane];
    float bb1 = db1[lane];
    float ob  = db2[c];
    int v0 = blockIdx.x * 4 + wave;
    int stride = gridDim.x * 4;
    for (int v = v0; v < N; v += stride) {
        int start = rowptr[v], cnt = counts[v];
        float dv = dinv[v];
        float acc = dv * Yin[(size_t)v * 64 + lane];
        for (int base = 0; base < cnt; base += 64) {
            int nb = min(64, cnt - base);
            int idx = 0; float ds = 0.f;
            if (lane < nb) {
                int2 e = edges[start + base + lane];
                idx = e.x;
                ds  = __int_as_float(e.y);
            }
            for (int jj = 0; jj < nb; ++jj) {
                int s = __shfl(idx, jj);
                float d = __shfl(ds, jj);
                acc = fmaf(d, Yin[(size_t)s * 64 + lane], acc);
            }
        }
        float h2 = fmaxf(fmaf(dv, acc, bbl), 0.f);   // relu(agg + b2)
        float a1 = bb1;
#pragma unroll
        for (int k = 0; k < 64; ++k)
            a1 = fmaf(__shfl(h2, k), D1[k * 64 + lane], a1);
        a1 = fmaxf(a1, 0.f);
        float o = 0.f;
#pragma unroll
        for (int kk = 0; kk < 16; ++kk)
            o = fmaf(__shfl(a1, part * 16 + kk), d2r[kk], o);
        o += __shfl_xor(o, 16);
        o += __shfl_xor(o, 32);
        if (lane < 16) out[(size_t)v * 16 + lane] = o + ob;
    }
}

// ---------------- launch ----------------

extern "C" void kernel_launch(void* const* d_in, const int* in_sizes, int n_in,
                              void* d_out, int out_size, void* d_ws, size_t ws_size,
                              hipStream_t stream) {
    const float* x   = (const float*)d_in[0];
    const int*   ei  = (const int*)d_in[1];
    const float* W1  = (const float*)d_in[2];
    const float* b1  = (const float*)d_in[3];
    const float* W2  = (const float*)d_in[4];
    const float* b2  = (const float*)d_in[5];
    const float* dW1 = (const float*)d_in[6];
    const float* db1 = (const float*)d_in[7];
    const float* dW2 = (const float*)d_in[8];
    const float* db2 = (const float*)d_in[9];
    float* out = (float*)d_out;

    int N = in_sizes[0] / 64;
    int E = in_sizes[1] / 2;
    const int* src = ei;
    const int* dst = ei + E;

    size_t off = 0;
    auto alloc = [&](size_t bytes) {
        void* p = (char*)d_ws + off;
        off += (bytes + 511) & ~(size_t)511;
        return p;
    };
    // counts and fillc contiguous -> one memset covers both
    int Npad = (N + 127) & ~127;                       // keep 512B alignment
    int*   counts = (int*)alloc((size_t)Npad * 8);     // [counts | fillc]
    int*   fillc  = counts + Npad;
    int*   rowptr = (int*)alloc((size_t)N * 4);
    int*   bsums  = (int*)alloc(512 * 4);
    int2*  edges  = (int2*)alloc((size_t)E * 8);
    float* dinv   = (float*)alloc((size_t)N * 4);
    float* xw     = (float*)alloc((size_t)N * 64 * 4);
    float* yw     = (float*)alloc((size_t)N * 64 * 4);

    hipMemsetAsync(counts, 0, (size_t)Npad * 8, stream);

    int nbN = (N + 255) / 256;
    int nbE = (E + 255) / 256;

    count_kernel<<<nbE, 256, 0, stream>>>(dst, counts, E);
    scan_local<<<nbN, 256, 0, stream>>>(counts, rowptr, bsums, dinv, N);
    scan_bsums<<<1, 512, 0, stream>>>(bsums, nbN);
    scan_add<<<nbN, 256, 0, stream>>>(rowptr, bsums, N);
    fill_kernel<<<nbE, 256, 0, stream>>>(src, dst, rowptr, fillc, dinv, edges, E);

    gemm64_kernel<<<4096, 128, 0, stream>>>(x, W1, xw, N);
    agg_mm_kernel<<<2048, 256, 0, stream>>>(xw, edges, rowptr, counts, dinv, b1, W2, yw, N);
    agg_head_kernel<<<2048, 256, 0, stream>>>(yw, edges, rowptr, counts, dinv, b2,
                                              dW1, db1, dW2, db2, out, N);
}

// Round 14
// 581.738 us; speedup vs baseline: 1.1943x; 1.1462x over previous
//
#include <hip/hip_runtime.h>

// ---------------- CSR construction (R13, unchanged) ----------------

__global__ void count_kernel(const int* __restrict__ dst, int* __restrict__ counts, int E) {
    int e = blockIdx.x * 256 + threadIdx.x;
    if (e < E) atomicAdd(&counts[dst[e]], 1);
}

__global__ void scan_local(const int* __restrict__ counts, int* __restrict__ rowptr,
                           int* __restrict__ bsums, float* __restrict__ dinv, int N) {
    __shared__ int sm[256];
    int t = threadIdx.x;
    int gid = blockIdx.x * 256 + t;
    int v = (gid < N) ? counts[gid] : 0;
    if (gid < N) dinv[gid] = rsqrtf((float)v + 1.0f);
    int x = v;
    sm[t] = x; __syncthreads();
    for (int off = 1; off < 256; off <<= 1) {
        int y = (t >= off) ? sm[t - off] : 0;
        __syncthreads();
        x += y; sm[t] = x; __syncthreads();
    }
    if (gid < N) rowptr[gid] = x - v;
    if (t == 255) bsums[blockIdx.x] = x;
}

__global__ void scan_bsums(int* bsums, int nb) {
    __shared__ int sm[512];
    int t = threadIdx.x;
    int v = (t < nb) ? bsums[t] : 0;
    int x = v;
    sm[t] = x; __syncthreads();
    for (int off = 1; off < 512; off <<= 1) {
        int y = (t >= off) ? sm[t - off] : 0;
        __syncthreads();
        x += y; sm[t] = x; __syncthreads();
    }
    if (t < nb) bsums[t] = x - v;
}

__global__ void scan_add(int* __restrict__ rowptr, const int* __restrict__ bsums, int N) {
    int gid = blockIdx.x * 256 + threadIdx.x;
    if (gid < N) rowptr[gid] += bsums[blockIdx.x];
}

__global__ void fill_kernel(const int* __restrict__ src, const int* __restrict__ dst,
                            const int* __restrict__ rowptr, int* __restrict__ fillc,
                            const float* __restrict__ dinv,
                            int2* __restrict__ edges, int E) {
    int e = blockIdx.x * 256 + threadIdx.x;
    if (e < E) {
        int d = dst[e];
        int s = src[e];
        int pos = rowptr[d] + atomicAdd(&fillc[d], 1);
        edges[pos] = make_int2(s, __float_as_int(dinv[s]));
    }
}

// ---------------- xw = X @ W (R13 version, unchanged) ----------------

__global__ void __launch_bounds__(128)
gemm64_kernel(const float* __restrict__ X, const float* __restrict__ W,
              float* __restrict__ out, int N) {
    __shared__ float Wl[64 * 64];
    __shared__ float hbuf[2][256];
    int tid = threadIdx.x;
    int lane = tid & 63;
    for (int i = tid; i < 4096; i += 128) Wl[i] = W[i];
    __syncthreads();
    int wi = __builtin_amdgcn_readfirstlane(tid >> 6);
    float* hb = &hbuf[wi][0];
    int g0 = blockIdx.x * 2 + wi;
    int ng = gridDim.x * 2;
    int NG = (N + 3) >> 2;
    for (int g = g0; g < NG; g += ng) {
        int v0 = g * 4;
        float x0 = (v0 + 0 < N) ? X[(size_t)(v0 + 0) * 64 + lane] : 0.f;
        float x1 = (v0 + 1 < N) ? X[(size_t)(v0 + 1) * 64 + lane] : 0.f;
        float x2 = (v0 + 2 < N) ? X[(size_t)(v0 + 2) * 64 + lane] : 0.f;
        float x3 = (v0 + 3 < N) ? X[(size_t)(v0 + 3) * 64 + lane] : 0.f;
        *(float4*)&hb[lane * 4] = make_float4(x0, x1, x2, x3);
        float y0 = 0.f, y1 = 0.f, y2 = 0.f, y3 = 0.f;
#pragma unroll 8
        for (int k = 0; k < 64; ++k) {
            float4 hk = *(const float4*)&hb[k * 4];
            float w = Wl[k * 64 + lane];
            y0 = fmaf(hk.x, w, y0);
            y1 = fmaf(hk.y, w, y1);
            y2 = fmaf(hk.z, w, y2);
            y3 = fmaf(hk.w, w, y3);
        }
        if (v0 + 0 < N) out[(size_t)(v0 + 0) * 64 + lane] = y0;
        if (v0 + 1 < N) out[(size_t)(v0 + 1) * 64 + lane] = y1;
        if (v0 + 2 < N) out[(size_t)(v0 + 2) * 64 + lane] = y2;
        if (v0 + 3 < N) out[(size_t)(v0 + 3) * 64 + lane] = y3;
    }
}

// ------- layer1 agg + @W2: TWO nodes per wave = 2 independent gather chains -------
// Per j-iteration: one gather per node (2 loads in flight per vmcnt wait vs 1).
// Guards on j<nb are wave-uniform (scalar branch, no divergence). rowptr/counts
// forced to SGPRs via readfirstlane to keep live VGPRs <=64 (occupancy cliff).

__global__ void agg_mm_kernel(const float* __restrict__ XW, const int2* __restrict__ edges,
                              const int* __restrict__ rowptr, const int* __restrict__ counts,
                              const float* __restrict__ dinv, const float* __restrict__ bias,
                              const float* __restrict__ W2, float* __restrict__ Y, int N) {
    __shared__ float Wl[64 * 64];
    int tid = threadIdx.x;
    for (int i = tid; i < 4096; i += 256) Wl[i] = W2[i];
    __syncthreads();
    int lane = tid & 63, wave = tid >> 6;
    float bb = bias[lane];
    int NP = (N + 1) >> 1;
    int p0 = blockIdx.x * 4 + wave;
    int pstr = gridDim.x * 4;
    for (int p = p0; p < NP; p += pstr) {
        int vA = 2 * p, vB = 2 * p + 1;
        bool hasB = vB < N;
        int startA = __builtin_amdgcn_readfirstlane(rowptr[vA]);
        int cntA   = __builtin_amdgcn_readfirstlane(counts[vA]);
        int startB = hasB ? __builtin_amdgcn_readfirstlane(rowptr[vB]) : 0;
        int cntB   = hasB ? __builtin_amdgcn_readfirstlane(counts[vB]) : 0;
        float dvA = dinv[vA];
        float dvB = hasB ? dinv[vB] : 0.f;
        float accA = dvA * XW[(size_t)vA * 64 + lane];
        float accB = hasB ? dvB * XW[(size_t)vB * 64 + lane] : 0.f;
        int cntM = max(cntA, cntB);
        for (int base = 0; base < cntM; base += 64) {
            int nbA = min(64, cntA - base);
            int nbB = min(64, cntB - base);
            int idxA = 0, idxB = 0; float dsA = 0.f, dsB = 0.f;
            if (lane < nbA) { int2 e = edges[startA + base + lane]; idxA = e.x; dsA = __int_as_float(e.y); }
            if (lane < nbB) { int2 e = edges[startB + base + lane]; idxB = e.x; dsB = __int_as_float(e.y); }
            int nbM = max(nbA, nbB);
            for (int j = 0; j < nbM; ++j) {
                if (j < nbA) {
                    int s = __shfl(idxA, j); float d = __shfl(dsA, j);
                    accA = fmaf(d, XW[(size_t)s * 64 + lane], accA);
                }
                if (j < nbB) {
                    int s = __shfl(idxB, j); float d = __shfl(dsB, j);
                    accB = fmaf(d, XW[(size_t)s * 64 + lane], accB);
                }
            }
        }
        float hA = fmaxf(fmaf(dvA, accA, bb), 0.f);
        float hB = fmaxf(fmaf(dvB, accB, bb), 0.f);
        float yA = 0.f, yB = 0.f;
#pragma unroll 8
        for (int k = 0; k < 64; ++k) {
            float w = Wl[k * 64 + lane];
            yA = fmaf(__shfl(hA, k), w, yA);
            yB = fmaf(__shfl(hB, k), w, yB);
        }
        Y[(size_t)vA * 64 + lane] = yA;
        if (hasB) Y[(size_t)vB * 64 + lane] = yB;
    }
}

// ------- layer2 agg + MLP head: TWO nodes per wave -------

__global__ void agg_head_kernel(const float* __restrict__ Yin, const int2* __restrict__ edges,
                                const int* __restrict__ rowptr, const int* __restrict__ counts,
                                const float* __restrict__ dinv, const float* __restrict__ b2,
                                const float* __restrict__ dW1, const float* __restrict__ db1,
                                const float* __restrict__ dW2, const float* __restrict__ db2,
                                float* __restrict__ out, int N) {
    __shared__ float D1[64 * 64];
    __shared__ float W2l[64 * 16];
    int tid = threadIdx.x;
    for (int i = tid; i < 4096; i += 256) D1[i] = dW1[i];
    for (int i = tid; i < 1024; i += 256) W2l[i] = dW2[i];
    __syncthreads();
    int lane = tid & 63, wave = tid >> 6;
    int c = lane & 15, part = lane >> 4;
    float bbl = b2[lane];
    float bb1 = db1[lane];
    float ob  = db2[c];
    int NP = (N + 1) >> 1;
    int p0 = blockIdx.x * 4 + wave;
    int pstr = gridDim.x * 4;
    for (int p = p0; p < NP; p += pstr) {
        int vA = 2 * p, vB = 2 * p + 1;
        bool hasB = vB < N;
        int startA = __builtin_amdgcn_readfirstlane(rowptr[vA]);
        int cntA   = __builtin_amdgcn_readfirstlane(counts[vA]);
        int startB = hasB ? __builtin_amdgcn_readfirstlane(rowptr[vB]) : 0;
        int cntB   = hasB ? __builtin_amdgcn_readfirstlane(counts[vB]) : 0;
        float dvA = dinv[vA];
        float dvB = hasB ? dinv[vB] : 0.f;
        float accA = dvA * Yin[(size_t)vA * 64 + lane];
        float accB = hasB ? dvB * Yin[(size_t)vB * 64 + lane] : 0.f;
        int cntM = max(cntA, cntB);
        for (int base = 0; base < cntM; base += 64) {
            int nbA = min(64, cntA - base);
            int nbB = min(64, cntB - base);
            int idxA = 0, idxB = 0; float dsA = 0.f, dsB = 0.f;
            if (lane < nbA) { int2 e = edges[startA + base + lane]; idxA = e.x; dsA = __int_as_float(e.y); }
            if (lane < nbB) { int2 e = edges[startB + base + lane]; idxB = e.x; dsB = __int_as_float(e.y); }
            int nbM = max(nbA, nbB);
            for (int j = 0; j < nbM; ++j) {
                if (j < nbA) {
                    int s = __shfl(idxA, j); float d = __shfl(dsA, j);
                    accA = fmaf(d, Yin[(size_t)s * 64 + lane], accA);
                }
                if (j < nbB) {
                    int s = __shfl(idxB, j); float d = __shfl(dsB, j);
                    accB = fmaf(d, Yin[(size_t)s * 64 + lane], accB);
                }
            }
        }
        float hA = fmaxf(fmaf(dvA, accA, bbl), 0.f);
        float hB = fmaxf(fmaf(dvB, accB, bbl), 0.f);
        float aA = bb1, aB = bb1;
#pragma unroll 8
        for (int k = 0; k < 64; ++k) {
            float w = D1[k * 64 + lane];
            aA = fmaf(__shfl(hA, k), w, aA);
            aB = fmaf(__shfl(hB, k), w, aB);
        }
        aA = fmaxf(aA, 0.f); aB = fmaxf(aB, 0.f);
        float oA = 0.f, oB = 0.f;
#pragma unroll 8
        for (int kk = 0; kk < 16; ++kk) {
            float w = W2l[(part * 16 + kk) * 16 + c];
            oA = fmaf(__shfl(aA, part * 16 + kk), w, oA);
            oB = fmaf(__shfl(aB, part * 16 + kk), w, oB);
        }
        oA += __shfl_xor(oA, 16); oA += __shfl_xor(oA, 32);
        oB += __shfl_xor(oB, 16); oB += __shfl_xor(oB, 32);
        if (lane < 16) {
            out[(size_t)vA * 16 + lane] = oA + ob;
            if (hasB) out[(size_t)vB * 16 + lane] = oB + ob;
        }
    }
}

// ---------------- launch ----------------

extern "C" void kernel_launch(void* const* d_in, const int* in_sizes, int n_in,
                              void* d_out, int out_size, void* d_ws, size_t ws_size,
                              hipStream_t stream) {
    const float* x   = (const float*)d_in[0];
    const int*   ei  = (const int*)d_in[1];
    const float* W1  = (const float*)d_in[2];
    const float* b1  = (const float*)d_in[3];
    const float* W2  = (const float*)d_in[4];
    const float* b2  = (const float*)d_in[5];
    const float* dW1 = (const float*)d_in[6];
    const float* db1 = (const float*)d_in[7];
    const float* dW2 = (const float*)d_in[8];
    const float* db2 = (const float*)d_in[9];
    float* out = (float*)d_out;

    int N = in_sizes[0] / 64;
    int E = in_sizes[1] / 2;
    const int* src = ei;
    const int* dst = ei + E;

    size_t off = 0;
    auto alloc = [&](size_t bytes) {
        void* p = (char*)d_ws + off;
        off += (bytes + 511) & ~(size_t)511;
        return p;
    };
    int Npad = (N + 127) & ~127;
    int*   counts = (int*)alloc((size_t)Npad * 8);     // [counts | fillc]
    int*   fillc  = counts + Npad;
    int*   rowptr = (int*)alloc((size_t)N * 4);
    int*   bsums  = (int*)alloc(512 * 4);
    int2*  edges  = (int2*)alloc((size_t)E * 8);
    float* dinv   = (float*)alloc((size_t)N * 4);
    float* xw     = (float*)alloc((size_t)N * 64 * 4);
    float* yw     = (float*)alloc((size_t)N * 64 * 4);

    hipMemsetAsync(counts, 0, (size_t)Npad * 8, stream);

    int nbN = (N + 255) / 256;
    int nbE = (E + 255) / 256;

    count_kernel<<<nbE, 256, 0, stream>>>(dst, counts, E);
    scan_local<<<nbN, 256, 0, stream>>>(counts, rowptr, bsums, dinv, N);
    scan_bsums<<<1, 512, 0, stream>>>(bsums, nbN);
    scan_add<<<nbN, 256, 0, stream>>>(rowptr, bsums, N);
    fill_kernel<<<nbE, 256, 0, stream>>>(src, dst, rowptr, fillc, dinv, edges, E);

    gemm64_kernel<<<4096, 128, 0, stream>>>(x, W1, xw, N);
    agg_mm_kernel<<<2048, 256, 0, stream>>>(xw, edges, rowptr, counts, dinv, b1, W2, yw, N);
    agg_head_kernel<<<2048, 256, 0, stream>>>(yw, edges, rowptr, counts, dinv, b2,
                                              dW1, db1, dW2, db2, out, N);
}